// Round 4
// baseline (19.885 us; speedup 1.0000x reference)
//
#include <hip/hip_runtime.h>

#define NROWS  65536
#define NCLS   256
#define NBLK   2048

__global__ __launch_bounds__(256) void OrdinalLoss_main_kernel(
    const float* __restrict__ pred, const int* __restrict__ tgt,
    float* __restrict__ partial, int nrows)
{
    const int tid    = blockIdx.x * blockDim.x + threadIdx.x;
    const int lane   = threadIdx.x & 63;
    const int g      = lane >> 4;        // row within 4-row pack
    const int li     = lane & 15;        // lane within 16-lane row group
    const int wave   = tid >> 6;
    const int nwaves = (gridDim.x * blockDim.x) >> 6;

    float acc = 0.0f;

    // ---- distributed gather: 8 rows per wave via lanes 0..7 ----
    if (lane < 8) {
        for (int r = wave * 8 + lane; r < nrows; r += nwaves * 8)
            acc = -pred[(size_t)r * NCLS + tgt[r]];
    }

    // ---- per-lane column constants: col = li*4 + (k>>2)*64 + (k&3) ----
    const float j0 = (float)(li * 4);
    float c[16], c2[16];
    #pragma unroll
    for (int k = 0; k < 16; ++k) {
        const float col = j0 + (float)((k >> 2) * 64 + (k & 3));
        c[k]  = col;
        c2[k] = col * col;
    }

    // moment accumulation: s0=sum e, s1=sum e*j, s2=sum e*j^2 (4 ops/elem)
    #define TERM(S0, S1, S2, PV, K) { float e = __expf(PV); S0 += e;        \
                                      S1 = fmaf(e, c[K],  S1);              \
                                      S2 = fmaf(e, c2[K], S2); }
    #define PACK16(S0, S1, S2, Q0, Q1, Q2, Q3)                              \
        TERM(S0,S1,S2, Q0.x, 0)  TERM(S0,S1,S2, Q0.y, 1)                    \
        TERM(S0,S1,S2, Q0.z, 2)  TERM(S0,S1,S2, Q0.w, 3)                    \
        TERM(S0,S1,S2, Q1.x, 4)  TERM(S0,S1,S2, Q1.y, 5)                    \
        TERM(S0,S1,S2, Q1.z, 6)  TERM(S0,S1,S2, Q1.w, 7)                    \
        TERM(S0,S1,S2, Q2.x, 8)  TERM(S0,S1,S2, Q2.y, 9)                    \
        TERM(S0,S1,S2, Q2.z,10)  TERM(S0,S1,S2, Q2.w,11)                    \
        TERM(S0,S1,S2, Q3.x,12)  TERM(S0,S1,S2, Q3.y,13)                    \
        TERM(S0,S1,S2, Q3.z,14)  TERM(S0,S1,S2, Q3.w,15)

    #define REDUCE_ROW(S0, S1, S2, T)                                       \
        _Pragma("unroll")                                                   \
        for (int m = 8; m; m >>= 1) {                                       \
            S0 += __shfl_xor(S0, m);                                        \
            S1 += __shfl_xor(S1, m);                                        \
            S2 += __shfl_xor(S2, m);                                        \
        }                                                                   \
        if (li == 0) {                                                      \
            const float tf = (float)(T);                                    \
            acc += __logf(S0) + (S2 - 2.0f * tf * S1 + tf * tf * S0) / S0;  \
        }

    const int npacks = nrows >> 2;
    int pack = wave;
    // ---- dual-pack pipeline: all 8 row-loads + 2 tgt loads in flight ----
    for (; pack + nwaves < npacks; pack += 2 * nwaves) {
        const int rowA = pack * 4 + g;
        const int rowB = (pack + nwaves) * 4 + g;
        const float* rpA = pred + (size_t)rowA * NCLS + li * 4;
        const float* rpB = pred + (size_t)rowB * NCLS + li * 4;
        const float4 a0 = *reinterpret_cast<const float4*>(rpA);
        const float4 a1 = *reinterpret_cast<const float4*>(rpA + 64);
        const float4 a2 = *reinterpret_cast<const float4*>(rpA + 128);
        const float4 a3 = *reinterpret_cast<const float4*>(rpA + 192);
        const float4 b0 = *reinterpret_cast<const float4*>(rpB);
        const float4 b1 = *reinterpret_cast<const float4*>(rpB + 64);
        const float4 b2 = *reinterpret_cast<const float4*>(rpB + 128);
        const float4 b3 = *reinterpret_cast<const float4*>(rpB + 192);
        const int tA = tgt[rowA];
        const int tB = tgt[rowB];

        float sA0 = 0.0f, sA1 = 0.0f, sA2 = 0.0f;
        float sB0 = 0.0f, sB1 = 0.0f, sB2 = 0.0f;
        PACK16(sA0, sA1, sA2, a0, a1, a2, a3)
        PACK16(sB0, sB1, sB2, b0, b1, b2, b3)
        REDUCE_ROW(sA0, sA1, sA2, tA)
        REDUCE_ROW(sB0, sB1, sB2, tB)
    }
    // ---- tail: single pack ----
    if (pack < npacks) {
        const int rowA = pack * 4 + g;
        const float* rpA = pred + (size_t)rowA * NCLS + li * 4;
        const float4 a0 = *reinterpret_cast<const float4*>(rpA);
        const float4 a1 = *reinterpret_cast<const float4*>(rpA + 64);
        const float4 a2 = *reinterpret_cast<const float4*>(rpA + 128);
        const float4 a3 = *reinterpret_cast<const float4*>(rpA + 192);
        const int tA = tgt[rowA];
        float sA0 = 0.0f, sA1 = 0.0f, sA2 = 0.0f;
        PACK16(sA0, sA1, sA2, a0, a1, a2, a3)
        REDUCE_ROW(sA0, sA1, sA2, tA)
    }
    #undef TERM
    #undef PACK16
    #undef REDUCE_ROW

    // ---- block reduce + ONE plain store per block (no atomics) ----
    __shared__ float red[256];
    red[threadIdx.x] = acc;
    __syncthreads();
    if (threadIdx.x < 64) {
        float v = red[threadIdx.x] + red[threadIdx.x + 64] +
                  red[threadIdx.x + 128] + red[threadIdx.x + 192];
        #pragma unroll
        for (int mask = 32; mask; mask >>= 1)
            v += __shfl_xor(v, mask);
        if (threadIdx.x == 0)
            partial[blockIdx.x] = v;
    }
}

__global__ __launch_bounds__(256) void OrdinalLoss_final_kernel(
    const float* __restrict__ partial, float* __restrict__ out)
{
    float v = 0.0f;
    #pragma unroll
    for (int i = 0; i < NBLK / 256; ++i)
        v += partial[threadIdx.x + i * 256];

    __shared__ float red[256];
    red[threadIdx.x] = v;
    __syncthreads();
    if (threadIdx.x < 64) {
        float s = red[threadIdx.x] + red[threadIdx.x + 64] +
                  red[threadIdx.x + 128] + red[threadIdx.x + 192];
        #pragma unroll
        for (int mask = 32; mask; mask >>= 1)
            s += __shfl_xor(s, mask);
        if (threadIdx.x == 0)
            out[0] = s * (1.0f / (float)NROWS);
    }
}

extern "C" void kernel_launch(void* const* d_in, const int* in_sizes, int n_in,
                              void* d_out, int out_size, void* d_ws, size_t ws_size,
                              hipStream_t stream) {
    const float* pred = (const float*)d_in[0];
    const int*   tgt  = (const int*)d_in[1];
    float*       out  = (float*)d_out;
    float*       ws   = (float*)d_ws;      // NBLK floats, fully overwritten each call
    const int nrows   = in_sizes[1];       // 65536 targets

    OrdinalLoss_main_kernel<<<NBLK, 256, 0, stream>>>(pred, tgt, ws, nrows);
    OrdinalLoss_final_kernel<<<1, 256, 0, stream>>>(ws, out);
}